// Round 12
// baseline (54.019 us; speedup 1.0000x reference)
//
#include <hip/hip_runtime.h>
#include <math.h>

#define K_TOP 16
#define D_DIM 1024
#define N_ROWS 2048                       // 32 * 64 rows

typedef float f32x4 __attribute__((ext_vector_type(4)));

// One block (512 thr = 8 waves) per row q.
//   waves 0..6: zero k-rows 2w, 2w+1 (8 x 1KB unrolled f32x4 stores each,
//     issued from cycle ~0; 87.5% of store traffic early, 7 issue streams).
//   wave 7:     load logits[r]+gn[q] (f32x4, lane owns d=lane*16+j),
//     16 rounds of {per-lane masked argmax -> 64-lane butterfly argmax}
//     (tie-break smaller index), rank-sort ascending, publish sel to LDS,
//     then write k-rows 14..15 with the 1.0 MERGED into its own burst.
//   One __syncthreads (per-wave store drain), then wave 7 lanes 0..13
//   scatter the ones for k-rows 0..13 into L2-dirty lines.
__global__ __launch_bounds__(512) void dps_topk_kernel(
    const float* __restrict__ logits,  // (64, 1024)
    const float* __restrict__ gn,      // (32, 64, 1024)
    float* __restrict__ out)           // (32, 64, 16, 1024)
{
    const int tid  = threadIdx.x;
    const int lane = tid & 63;
    const int wave = tid >> 6;          // 0..7
    const int q    = blockIdx.x;
    const int r    = q & 63;

    __shared__ int sel_lds[K_TOP];

    float* orow = out + (size_t)q * (K_TOP * D_DIM);
    f32x4* o4   = reinterpret_cast<f32x4*>(orow);
    const f32x4 zero = {0.f, 0.f, 0.f, 0.f};

    if (wave < 7) {
        // ---- zero k-rows 2w and 2w+1: 512 f32x4, 8 stores per lane ----
        f32x4* base = o4 + wave * 512 + lane;
        #pragma unroll
        for (int i = 0; i < 8; ++i) base[i * 64] = zero;
    } else {
        // ---- selector: load + perturb (lane owns 16 consecutive) ----
        float v[16];
        {
            const f32x4* l4 = reinterpret_cast<const f32x4*>(
                logits + (size_t)r * D_DIM + lane * 16);
            const f32x4* g4 = reinterpret_cast<const f32x4*>(
                gn + (size_t)q * D_DIM + lane * 16);
            #pragma unroll
            for (int c = 0; c < 4; ++c) {
                const f32x4 a = l4[c];
                const f32x4 b = g4[c];
                v[c * 4 + 0] = a.x + b.x;
                v[c * 4 + 1] = a.y + b.y;
                v[c * 4 + 2] = a.z + b.z;
                v[c * 4 + 3] = a.w + b.w;
            }
        }

        // ---- 16 rounds of wave-wide argmax ----
        unsigned chosen = 0;   // bitmask of already-taken j's in THIS lane
        int my_sel = 0;        // lane k ends up holding round-k winner
        for (int round = 0; round < K_TOP; ++round) {
            float bv = -INFINITY;
            int   bi = 0x7fffffff;
            #pragma unroll
            for (int j = 0; j < 16; ++j) {
                if (!(chosen & (1u << j))) {
                    // strict > keeps smaller j (= smaller index) on ties
                    if (v[j] > bv) { bv = v[j]; bi = lane * 16 + j; }
                }
            }
            #pragma unroll
            for (int off = 32; off > 0; off >>= 1) {
                const float ov = __shfl_xor(bv, off);
                const int   oi = __shfl_xor(bi, off);
                if (ov > bv || (ov == bv && oi < bi)) { bv = ov; bi = oi; }
            }
            if (lane == (bi >> 4)) chosen |= 1u << (bi & 15);
            if (lane == round)     my_sel = bi;
        }

        // ---- rank among the 16 winners = ascending index order ----
        int rank = 0;
        #pragma unroll
        for (int j = 0; j < K_TOP; ++j) {
            const int other = __shfl(my_sel, j);
            rank += (other < my_sel) ? 1 : 0;
        }
        if (lane < K_TOP) sel_lds[rank] = my_sel;

        // ---- fetch winners of k-rows 14,15 via broadcast shuffles ----
        int s14 = 0, s15 = 0;
        #pragma unroll
        for (int j = 0; j < K_TOP; ++j) {
            const int rj = __shfl(rank,   j);
            const int sj = __shfl(my_sel, j);
            if (rj == 14) s14 = sj;
            if (rj == 15) s15 = sj;
        }

        // ---- write k-rows 14,15 with the 1.0 merged into the burst ----
        int sel2[2];
        sel2[0] = s14; sel2[1] = s15;
        #pragma unroll
        for (int kk = 0; kk < 2; ++kk) {
            const int s  = sel2[kk];
            const int sv = s >> 2;
            f32x4 hot;
            hot.x = ((s & 3) == 0) ? 1.0f : 0.0f;
            hot.y = ((s & 3) == 1) ? 1.0f : 0.0f;
            hot.z = ((s & 3) == 2) ? 1.0f : 0.0f;
            hot.w = ((s & 3) == 3) ? 1.0f : 0.0f;
            f32x4* krow = o4 + (14 + kk) * 256;
            #pragma unroll
            for (int c = 0; c < 4; ++c) {
                const int f4idx = c * 64 + lane;
                krow[f4idx] = (f4idx == sv) ? hot : zero;
            }
        }
    }

    __syncthreads();   // zeros for k-rows 0..13 ACK'd; sel_lds visible

    // ---- scatter ones for k-rows 0..13 ----
    if (wave == 7 && lane < 14) {
        orow[lane * D_DIM + sel_lds[lane]] = 1.0f;
    }
}

extern "C" void kernel_launch(void* const* d_in, const int* in_sizes, int n_in,
                              void* d_out, int out_size, void* d_ws, size_t ws_size,
                              hipStream_t stream) {
    const float* logits = (const float*)d_in[0];  // (64, 1024) f32
    const float* gn     = (const float*)d_in[1];  // (32, 64, 1024) f32
    float* out          = (float*)d_out;          // (32, 64, 16, 1024) f32

    dps_topk_kernel<<<dim3(N_ROWS), dim3(512), 0, stream>>>(logits, gn, out);
}

// Round 13
// 34.499 us; speedup vs baseline: 1.5658x; 1.5658x over previous
//
#include <hip/hip_runtime.h>
#include <math.h>

#define K_TOP 16
#define D_DIM 1024
#define N_ROWS 2048                       // 32 * 64 rows

typedef float f32x4 __attribute__((ext_vector_type(4)));

// One block (256 thr) per row q — the measured-best structure (33.2 us):
//   waves 1..3: zero k-rows (w-1)*4..(w-1)*4+3 immediately (16 x 1KB
//               unrolled f32x4 stores from cycle ~0; 48 KB early).
//   wave 0:     load logits[r]+gn[q] (f32x4, lane owns d=lane*16+j),
//               16 rounds of {per-lane masked argmax -> 64-lane butterfly}
//               (tie-break smaller index), rank-sort ascending, publish to
//               LDS, then write k-rows 12..15 with the 1.0 MERGED into its
//               burst (no scatter needed for those rows).
//   one __syncthreads, then waves 1..3 (4 lanes each) scatter the 12 ones
//   for k-rows 0..11 into their own rows' lines.
__global__ __launch_bounds__(256) void dps_topk_kernel(
    const float* __restrict__ logits,  // (64, 1024)
    const float* __restrict__ gn,      // (32, 64, 1024)
    float* __restrict__ out)           // (32, 64, 16, 1024)
{
    const int tid  = threadIdx.x;
    const int lane = tid & 63;
    const int wave = tid >> 6;
    const int q    = blockIdx.x;
    const int r    = q & 63;

    __shared__ int sel_lds[K_TOP];

    float* orow = out + (size_t)q * (K_TOP * D_DIM);
    f32x4* o4   = reinterpret_cast<f32x4*>(orow);
    const f32x4 zero = {0.f, 0.f, 0.f, 0.f};

    if (wave != 0) {
        // ---- zero k-rows (wave-1)*4 .. +3 : 16 x 1KB stores, cycle ~0 ----
        f32x4* base = o4 + (wave - 1) * 1024 + lane;
        #pragma unroll
        for (int i = 0; i < 16; ++i) base[i * 64] = zero;
    } else {
        // ---- load + perturb: lane owns 16 consecutive elements (64 B) ----
        float v[16];
        {
            const f32x4* l4 = reinterpret_cast<const f32x4*>(
                logits + (size_t)r * D_DIM + lane * 16);
            const f32x4* g4 = reinterpret_cast<const f32x4*>(
                gn + (size_t)q * D_DIM + lane * 16);
            #pragma unroll
            for (int c = 0; c < 4; ++c) {
                const f32x4 a = l4[c];
                const f32x4 b = g4[c];
                v[c * 4 + 0] = a.x + b.x;
                v[c * 4 + 1] = a.y + b.y;
                v[c * 4 + 2] = a.z + b.z;
                v[c * 4 + 3] = a.w + b.w;
            }
        }

        // ---- 16 rounds of wave-wide argmax ----
        unsigned chosen = 0;   // bitmask of already-taken j's in THIS lane
        int my_sel = 0;        // lane k ends up holding round-k winner
        for (int round = 0; round < K_TOP; ++round) {
            float bv = -INFINITY;
            int   bi = 0x7fffffff;
            #pragma unroll
            for (int j = 0; j < 16; ++j) {
                if (!(chosen & (1u << j))) {
                    // strict > keeps smaller j (= smaller index) on ties
                    if (v[j] > bv) { bv = v[j]; bi = lane * 16 + j; }
                }
            }
            #pragma unroll
            for (int off = 32; off > 0; off >>= 1) {
                const float ov = __shfl_xor(bv, off);
                const int   oi = __shfl_xor(bi, off);
                if (ov > bv || (ov == bv && oi < bi)) { bv = ov; bi = oi; }
            }
            if (lane == (bi >> 4)) chosen |= 1u << (bi & 15);
            if (lane == round)     my_sel = bi;
        }

        // ---- rank among the 16 winners = ascending index order ----
        int rank = 0;
        #pragma unroll
        for (int j = 0; j < K_TOP; ++j) {
            const int other = __shfl(my_sel, j);
            rank += (other < my_sel) ? 1 : 0;
        }
        if (lane < K_TOP) sel_lds[rank] = my_sel;

        // ---- winners of k-rows 12..15 via broadcast shuffles ----
        int s12 = 0, s13 = 0, s14 = 0, s15 = 0;
        #pragma unroll
        for (int j = 0; j < K_TOP; ++j) {
            const int rj = __shfl(rank,   j);
            const int sj = __shfl(my_sel, j);
            if (rj == 12) s12 = sj;
            if (rj == 13) s13 = sj;
            if (rj == 14) s14 = sj;
            if (rj == 15) s15 = sj;
        }

        // ---- write k-rows 12..15 with the 1.0 merged into the burst ----
        int sel4[4];
        sel4[0] = s12; sel4[1] = s13; sel4[2] = s14; sel4[3] = s15;
        #pragma unroll
        for (int kk = 0; kk < 4; ++kk) {
            const int s  = sel4[kk];     // wave-uniform
            const int sv = s >> 2;       // which f32x4 holds the 1
            f32x4 hot;
            hot.x = ((s & 3) == 0) ? 1.0f : 0.0f;
            hot.y = ((s & 3) == 1) ? 1.0f : 0.0f;
            hot.z = ((s & 3) == 2) ? 1.0f : 0.0f;
            hot.w = ((s & 3) == 3) ? 1.0f : 0.0f;
            f32x4* krow = o4 + (12 + kk) * 256;
            #pragma unroll
            for (int c = 0; c < 4; ++c) {
                const int f4idx = c * 64 + lane;
                krow[f4idx] = (f4idx == sv) ? hot : zero;
            }
        }
    }

    __syncthreads();   // zeros for k-rows 0..11 ACK'd; sel_lds visible

    // ---- scatter ones for k-rows 0..11, spread across waves 1..3 ----
    if (wave != 0 && lane < 4) {
        const int k = (wave - 1) * 4 + lane;
        orow[k * D_DIM + sel_lds[k]] = 1.0f;
    }
}

extern "C" void kernel_launch(void* const* d_in, const int* in_sizes, int n_in,
                              void* d_out, int out_size, void* d_ws, size_t ws_size,
                              hipStream_t stream) {
    const float* logits = (const float*)d_in[0];  // (64, 1024) f32
    const float* gn     = (const float*)d_in[1];  // (32, 64, 1024) f32
    float* out          = (float*)d_out;          // (32, 64, 16, 1024) f32

    dps_topk_kernel<<<dim3(N_ROWS), dim3(256), 0, stream>>>(logits, gn, out);
}